// Round 7
// baseline (261.744 us; speedup 1.0000x reference)
//
#include <hip/hip_runtime.h>

typedef unsigned short u16;
typedef unsigned int u32;
typedef _Float16 half8 __attribute__((ext_vector_type(8)));
typedef __fp16 fp16x2 __attribute__((ext_vector_type(2)));
typedef float f32x16 __attribute__((ext_vector_type(16)));

union HU { uint4 u; half8 h; };
union PK { fp16x2 h; u32 u; };

__device__ __forceinline__ u16 f2h(float f) {
  union { _Float16 h; u16 u; } c;
  c.h = (_Float16)f;
  return c.u;
}

// async global->LDS DMA, 16 B per lane (lds dest = wave-uniform base + lane*16)
typedef const __attribute__((address_space(1))) u32 gu32;
typedef __attribute__((address_space(3))) u32 lu32;
__device__ __forceinline__ void gload_lds16(const void* g, void* l) {
  __builtin_amdgcn_global_load_lds((gu32*)g, (lu32*)l, 16, 0, 0);
}

// Pack weights (O=64, I=64, 3, 3) fp32 -> fp16 in exact A-fragment order:
// wbuf[((t*2 + mt)*64 + lane)*8 + j] = w[m][c][rs]
//   m = mt*32 + (lane&31), k = t*16 + (lane>>5)*8 + j, rs = k>>6, c = k&63
// K ordering: k = rs*64 + c (rs-major, c-minor); ktile t = rs*4 + Q (16-ch quarter).
__global__ void prep_w(const float* __restrict__ w, u16* __restrict__ wbuf) {
  int idx = blockIdx.x * 256 + threadIdx.x;  // 36864 total
  int j    = idx & 7;
  int lane = (idx >> 3) & 63;
  int mt   = (idx >> 9) & 1;
  int t    = idx >> 10;
  int m  = mt * 32 + (lane & 31);
  int k  = t * 16 + (lane >> 5) * 8 + j;
  int rs = k >> 6;
  int c  = k & 63;
  wbuf[idx] = f2h(w[(m * 64 + c) * 9 + rs]);
}

// Implicit-GEMM conv: M = O = 64, N = pixels, K = 576 in 4 quarters of 16 ch.
// v7: v6 post-mortem showed NO pipe >25% busy (MFMA 37K, LDS-read 55K,
// VALU ~20K of 230K cyc/CU) — the kernel is SERIALIZATION-bound: lockstep
// {stage -> barrier -> kloop} with only 2 blocks/CU of cross-block cover.
// Fix: same 1.0-reads/MFMA wave shape (64o x 64px, acc[2][2]), but block =
// 256 thr (4 waves = rw2 x np2), 2 output rows, SINGLE-buffered x and w:
//   LDS = x [row4][cblk2][slot130][ch8] 16,640 B + w 18,432 B = 35,072 B
//   -> 4 co-resident blocks/CU (16 waves). Four independent blocks
//   decorrelate their stage/kloop phases: while one block waits on its
//   stage loads, three others feed the MFMA/LDS pipes.
// Per phase: dma_w(Q) first (fire-and-forget, hides under x loads), then
// stage_x(Q) (4 tasks/wave = 32 back-to-back global dword loads), barrier,
// kloop(Q) = 9 x {2 A + 2 B ds_read_b128, 4 MFMA}.
// NOTHING held in registers across a kloop (r1/r4 spill lesson); acc[2][2]
// = 64 regs lives in the unified file; launch_bounds(256,4) = 128-reg
// budget (v6 compiled at 60 VGPR + acc under the same budget).
// Halo-padded pixel axis (slots 0/129 zeroed once) -> no bounds logic.
// All LDS ops lane-contiguous 16 B -> conflict-free.
// XCD swizzle: 2048 % 8 == 0; wg = (bid&7)*256 + bid>>3.
__global__ __launch_bounds__(256, 4) void conv_mfma(
    const float* __restrict__ x, const u16* __restrict__ wbuf,
    const float* __restrict__ bias, float* __restrict__ out) {
  __shared__ u16 xlds[8 * 130 * 8];   // 16,640 B
  __shared__ u16 wlds[18 * 512];      // 18,432 B

  int tid = threadIdx.x;
  int lane = tid & 63;
  int wave = tid >> 6;  // 0..3
  int bid = blockIdx.x;
  int wg = ((bid & 7) << 8) | (bid >> 3);  // bijective XCD-contiguous remap
  int nb = wg >> 6;        // batch [0,32)
  int hg = wg & 63;        // row-group [0,64)
  int h0 = hg * 2;

  int l31 = lane & 31;
  int half = lane >> 5;
  int rw = wave >> 1;   // output row within block (0..1)
  int np = wave & 1;    // ntile pair: pixels np*64 + {0,32} + l31

  // zero halo slots (0 and 129) of all 8 slabs, once; staging writes only
  // slots 1..128, so these stay zero across all 4 quarters.
  if (tid < 16) {
    int sl = tid >> 1, e = tid & 1;
    *(uint4*)&xlds[(sl * 130 + e * 129) * 8] = make_uint4(0u, 0u, 0u, 0u);
  }

  f32x16 acc[2][2] = {};  // [mt][ntile]

  // stage x channels Q*16..+15 for input rows h0-1..h0+2 -> xlds.
  // 16 tasks = (row4, cblk2, whalf2); each wave 4 -> 32 global loads in flight.
  auto stage_x = [&](int Q) {
#pragma unroll
    for (int s4 = 0; s4 < 4; ++s4) {
      int id = s4 * 4 + wave;     // 0..15
      int row = id >> 2;          // 0..3
      int cblk = (id >> 1) & 1;
      int wh = id & 1;
      int hin = h0 - 1 + row;
      int c0 = Q * 16 + cblk * 8;
      const float* base = x + (((size_t)(nb * 64 + c0) * 128 + hin) * 128);
      int wp = wh * 64 + lane;
      uint4 v = make_uint4(0u, 0u, 0u, 0u);
      if (hin >= 0 && hin < 128) {
        float f[8];
#pragma unroll
        for (int j = 0; j < 8; ++j) f[j] = base[(size_t)j * 16384 + wp];
        PK p0, p1, p2, p3;
        p0.h = __builtin_amdgcn_cvt_pkrtz(f[0], f[1]);
        p1.h = __builtin_amdgcn_cvt_pkrtz(f[2], f[3]);
        p2.h = __builtin_amdgcn_cvt_pkrtz(f[4], f[5]);
        p3.h = __builtin_amdgcn_cvt_pkrtz(f[6], f[7]);
        v = make_uint4(p0.u, p1.u, p2.u, p3.u);
      }
      *(uint4*)&xlds[((row * 2 + cblk) * 130 + 1 + wp) * 8] = v;
    }
  };

  // async-DMA quarter Q's 18 A-fragments (rs9 x mt2, 1 KB each) into wlds.
  auto dma_w = [&](int Q) {
#pragma unroll
    for (int s5 = 0; s5 < 5; ++s5) {
      int f = s5 * 4 + wave;  // 0..19, valid < 18
      if (f < 18) {
        int gf = (f >> 1) * 8 + Q * 2 + (f & 1);  // wbuf frag (rs*4+Q)*2+mt
        gload_lds16(&wbuf[gf * 512 + lane * 8], &wlds[f * 512]);
      }
    }
  };

  // 9 ktiles: per ktile {2 A + 2 B ds_read, 4 MFMA} = 1.0 reads/MFMA.
  auto kloop = [&]() {
#pragma unroll
    for (int r = 0; r < 3; ++r) {
      int row = rw + r;                 // staged row index 0..3
      int sb = (row * 2 + half) * 130;  // lane-half picks the cblk
#pragma unroll
      for (int s = 0; s < 3; ++s) {
        int rs = r * 3 + s;
        int ps = np * 64 + l31 + s;  // halo slot of ntile 0; ntile 1 at +32
        HU a0, a1, b0, b1;
        a0.u = *(const uint4*)&wlds[(rs * 2 + 0) * 512 + lane * 8];
        a1.u = *(const uint4*)&wlds[(rs * 2 + 1) * 512 + lane * 8];
        b0.u = *(const uint4*)&xlds[(sb + ps) * 8];
        b1.u = *(const uint4*)&xlds[(sb + ps + 32) * 8];
        acc[0][0] = __builtin_amdgcn_mfma_f32_32x32x16_f16(a0.h, b0.h, acc[0][0], 0, 0, 0);
        acc[0][1] = __builtin_amdgcn_mfma_f32_32x32x16_f16(a0.h, b1.h, acc[0][1], 0, 0, 0);
        acc[1][0] = __builtin_amdgcn_mfma_f32_32x32x16_f16(a1.h, b0.h, acc[1][0], 0, 0, 0);
        acc[1][1] = __builtin_amdgcn_mfma_f32_32x32x16_f16(a1.h, b1.h, acc[1][1], 0, 0, 0);
      }
    }
  };

  // ---- schedule: 4 quarters, fully single-buffered; cross-block overlap
  //      (4 blocks/CU) covers the stage windows and barriers ----
#pragma unroll
  for (int Q = 0; Q < 4; ++Q) {
    if (Q) __syncthreads();   // previous kloop must drain before overwrite
    dma_w(Q);                 // fire-and-forget DMA, hides under x loads
    stage_x(Q);               // 32 back-to-back global loads + pkrtz + ds_write
    __syncthreads();          // x + w visible
    kloop();
  }

  // ---- epilogue: C/D layout col = lane&31 (pixel), row = (reg&3)+8*(reg>>2)+4*half (o) ----
  int h = h0 + rw;
#pragma unroll
  for (int mt = 0; mt < 2; ++mt) {
#pragma unroll
    for (int i = 0; i < 2; ++i) {
      int p = np * 64 + i * 32 + l31;
      size_t ob = (size_t)nb * 64 * 16384 + (size_t)h * 128 + p;
#pragma unroll
      for (int reg = 0; reg < 16; ++reg) {
        int o = mt * 32 + (reg & 3) + 8 * (reg >> 2) + 4 * half;
        out[ob + (size_t)o * 16384] = acc[mt][i][reg] + bias[o];
      }
    }
  }
}

extern "C" void kernel_launch(void* const* d_in, const int* in_sizes, int n_in,
                              void* d_out, int out_size, void* d_ws, size_t ws_size,
                              hipStream_t stream) {
  const float* x = (const float*)d_in[0];
  const float* w = (const float*)d_in[1];
  const float* b = (const float*)d_in[2];
  float* out = (float*)d_out;
  u16* wbuf = (u16*)d_ws;  // 36864 fp16 = 73728 B of scratch

  prep_w<<<dim3(144), dim3(256), 0, stream>>>(w, wbuf);
  conv_mfma<<<dim3(2048), dim3(256), 0, stream>>>(x, wbuf, b, out);
}

// Round 8
// 253.337 us; speedup vs baseline: 1.0332x; 1.0332x over previous
//
#include <hip/hip_runtime.h>

typedef unsigned short u16;
typedef unsigned int u32;
typedef _Float16 half8 __attribute__((ext_vector_type(8)));
typedef __fp16 fp16x2 __attribute__((ext_vector_type(2)));
typedef float f32x16 __attribute__((ext_vector_type(16)));

union HU { uint4 u; half8 h; };
union PK { fp16x2 h; u32 u; };

__device__ __forceinline__ u16 f2h(float f) {
  union { _Float16 h; u16 u; } c;
  c.h = (_Float16)f;
  return c.u;
}

// async global->LDS DMA, 16 B per lane (lds dest = wave-uniform base + lane*16)
typedef const __attribute__((address_space(1))) u32 gu32;
typedef __attribute__((address_space(3))) u32 lu32;
__device__ __forceinline__ void gload_lds16(const void* g, void* l) {
  __builtin_amdgcn_global_load_lds((gu32*)g, (lu32*)l, 16, 0, 0);
}

// Pack weights (O=64, I=64, 3, 3) fp32 -> fp16 in exact A-fragment order:
// wbuf[((t*2 + mt)*64 + lane)*8 + j] = w[m][c][rs]
//   m = mt*32 + (lane&31), k = t*16 + (lane>>5)*8 + j, rs = k>>6, c = k&63
// K ordering: k = rs*64 + c (rs-major, c-minor); ktile t = rs*4 + Q (16-ch quarter).
__global__ void prep_w(const float* __restrict__ w, u16* __restrict__ wbuf) {
  int idx = blockIdx.x * 256 + threadIdx.x;  // 36864 total
  int j    = idx & 7;
  int lane = (idx >> 3) & 63;
  int mt   = (idx >> 9) & 1;
  int t    = idx >> 10;
  int m  = mt * 32 + (lane & 31);
  int k  = t * 16 + (lane >> 5) * 8 + j;
  int rs = k >> 6;
  int c  = k & 63;
  wbuf[idx] = f2h(w[(m * 64 + c) * 9 + rs]);
}

// Implicit-GEMM conv: M = O = 64, N = pixels, K = 576 in 4 quarters of 16 ch.
// v8: REGISTER-HEADROOM round. v5/v6/v7 all hit ~97 us with MfmaUtil ~15%
// because every config left the compiler 0 unified regs of slack
// (v7: 64 arch VGPR + 64 AGPR acc = exactly the 128 budget of (256,4)) ->
// no cross-ktile ds_read prefetch -> each ktile eats a full LDS round-trip.
// Fix: __launch_bounds__(256,2) -> 2 waves/SIMD, up to ~512 regs/wave.
// Headroom is spent on the full pipeline (r4's design, which spilled at
// budget 85 and is now affordable):
//   per quarter Q: {issue dma_w(Q+1) -> wlds[^1]; issue 32 x-loads(Q+1)
//   into regs} -> kloop(Q) from xlds[Q&1]/wlds[Q&1] -> {pkrtz + ds_write
//   x(Q+1) -> xlds[^1]} -> barrier.   4 barriers total (v7: 8).
// All global latency hides under kloop; kloop itself can now be
// software-pipelined by the compiler (fine-grained lgkmcnt, m97-style).
// Wave shape unchanged (1.0 LDS-reads/MFMA): (rw,np) computes 64o x 64px,
// acc[2][2] = 64 AGPRs. Block = 256 thr (4 waves), 2 output rows.
// LDS: xlds 2 x 16,640 + wlds 2 x 18,432 = 70,144 B -> 2 blocks/CU
// (8 waves/CU; deliberate ILP-for-TLP trade).
// Halo-padded pixel axis (slots 0/129 zeroed once per buffer).
// All LDS ops lane-contiguous 16 B -> conflict-free.
// XCD swizzle: 2048 % 8 == 0; wg = (bid&7)*256 + bid>>3.
__global__ __launch_bounds__(256, 2) void conv_mfma(
    const float* __restrict__ x, const u16* __restrict__ wbuf,
    const float* __restrict__ bias, float* __restrict__ out) {
  __shared__ u16 xlds[2][8 * 130 * 8];   // 2 x 16,640 B
  __shared__ u16 wlds[2][18 * 512];      // 2 x 18,432 B

  int tid = threadIdx.x;
  int lane = tid & 63;
  int wave = tid >> 6;  // 0..3
  int bid = blockIdx.x;
  int wg = ((bid & 7) << 8) | (bid >> 3);  // bijective XCD-contiguous remap
  int nb = wg >> 6;        // batch [0,32)
  int hg = wg & 63;        // row-group [0,64)
  int h0 = hg * 2;

  int l31 = lane & 31;
  int half = lane >> 5;
  int rw = wave >> 1;   // output row within block (0..1)
  int np = wave & 1;    // ntile pair: pixels np*64 + {0,32} + l31

  // zero halo slots (0 and 129) of all 8 slabs in BOTH buffers, once.
  if (tid < 32) {
    int b = (tid >> 4) & 1, sl = (tid >> 1) & 7, e = tid & 1;
    *(uint4*)&xlds[b][(sl * 130 + e * 129) * 8] = make_uint4(0u, 0u, 0u, 0u);
  }

  f32x16 acc[2][2] = {};  // [mt][ntile]

  // async-DMA quarter Q's 18 A-fragments (rs9 x mt2, 1 KB each) into wl.
  auto dma_w = [&](int Q, u16* wl) {
#pragma unroll
    for (int s5 = 0; s5 < 5; ++s5) {
      int f = s5 * 4 + wave;  // 0..19, valid < 18
      if (f < 18) {
        int gf = (f >> 1) * 8 + Q * 2 + (f & 1);  // wbuf frag (rs*4+Q)*2+mt
        gload_lds16(&wbuf[gf * 512 + lane * 8], &wl[f * 512]);
      }
    }
  };

  // 9 ktiles: per ktile {2 A + 2 B ds_read_b128, 4 MFMA} = 1.0 reads/MFMA.
  auto kloop = [&](const u16* xl, const u16* wl) {
#pragma unroll
    for (int r = 0; r < 3; ++r) {
      int row = rw + r;                 // staged row index 0..3
      int sb = (row * 2 + half) * 130;  // lane-half picks the cblk
#pragma unroll
      for (int s = 0; s < 3; ++s) {
        int rs = r * 3 + s;
        int ps = np * 64 + l31 + s;  // halo slot of ntile 0; ntile 1 at +32
        HU a0, a1, b0, b1;
        a0.u = *(const uint4*)&wl[(rs * 2 + 0) * 512 + lane * 8];
        a1.u = *(const uint4*)&wl[(rs * 2 + 1) * 512 + lane * 8];
        b0.u = *(const uint4*)&xl[(sb + ps) * 8];
        b1.u = *(const uint4*)&xl[(sb + ps + 32) * 8];
        acc[0][0] = __builtin_amdgcn_mfma_f32_32x32x16_f16(a0.h, b0.h, acc[0][0], 0, 0, 0);
        acc[0][1] = __builtin_amdgcn_mfma_f32_32x32x16_f16(a0.h, b1.h, acc[0][1], 0, 0, 0);
        acc[1][0] = __builtin_amdgcn_mfma_f32_32x32x16_f16(a1.h, b0.h, acc[1][0], 0, 0, 0);
        acc[1][1] = __builtin_amdgcn_mfma_f32_32x32x16_f16(a1.h, b1.h, acc[1][1], 0, 0, 0);
      }
    }
  };

  // ---- prologue: synchronous stage of quarter 0 ----
  dma_w(0, wlds[0]);
#pragma unroll
  for (int s4 = 0; s4 < 4; ++s4) {
    int id = s4 * 4 + wave;     // 16 tasks = (row4, cblk2, whalf2)
    int row = id >> 2, cblk = (id >> 1) & 1, wh = id & 1;
    int hin = h0 - 1 + row;
    const float* base = x + (((size_t)(nb * 64 + cblk * 8) * 128 + hin) * 128);
    int wp = wh * 64 + lane;
    uint4 v = make_uint4(0u, 0u, 0u, 0u);
    if (hin >= 0 && hin < 128) {
      float f[8];
#pragma unroll
      for (int j = 0; j < 8; ++j) f[j] = base[(size_t)j * 16384 + wp];
      PK p0, p1, p2, p3;
      p0.h = __builtin_amdgcn_cvt_pkrtz(f[0], f[1]);
      p1.h = __builtin_amdgcn_cvt_pkrtz(f[2], f[3]);
      p2.h = __builtin_amdgcn_cvt_pkrtz(f[4], f[5]);
      p3.h = __builtin_amdgcn_cvt_pkrtz(f[6], f[7]);
      v = make_uint4(p0.u, p1.u, p2.u, p3.u);
    }
    *(uint4*)&xlds[0][((row * 2 + cblk) * 130 + 1 + wp) * 8] = v;
  }
  __syncthreads();  // x(0) + w(0) visible

  // ---- pipelined quarters ----
#pragma unroll
  for (int Q = 0; Q < 4; ++Q) {
    float xf[4][8];   // next quarter's x, held across kloop (affordable at
    int inb[4];       // the (256,2) budget; r4's spill was at budget 85)

    if (Q < 3) {
      // issue-early: next quarter's weights (DMA) and x (to regs)
      dma_w(Q + 1, wlds[(Q + 1) & 1]);
#pragma unroll
      for (int s4 = 0; s4 < 4; ++s4) {
        int id = s4 * 4 + wave;
        int row = id >> 2, cblk = (id >> 1) & 1, wh = id & 1;
        int hin = h0 - 1 + row;
        inb[s4] = (hin >= 0 && hin < 128);
        int hc = hin < 0 ? 0 : (hin > 127 ? 127 : hin);  // clamped: load always
        const float* base =
            x + (((size_t)(nb * 64 + (Q + 1) * 16 + cblk * 8) * 128 + hc) * 128);
        int wp = wh * 64 + lane;
#pragma unroll
        for (int j = 0; j < 8; ++j) xf[s4][j] = base[(size_t)j * 16384 + wp];
      }
    }

    kloop(xlds[Q & 1], wlds[Q & 1]);

    if (Q < 3) {
      // write-late: convert + store next x-tile into the other buffer
#pragma unroll
      for (int s4 = 0; s4 < 4; ++s4) {
        int id = s4 * 4 + wave;
        int row = id >> 2, cblk = (id >> 1) & 1, wh = id & 1;
        int wp = wh * 64 + lane;
        uint4 v = make_uint4(0u, 0u, 0u, 0u);
        if (inb[s4]) {
          PK p0, p1, p2, p3;
          p0.h = __builtin_amdgcn_cvt_pkrtz(xf[s4][0], xf[s4][1]);
          p1.h = __builtin_amdgcn_cvt_pkrtz(xf[s4][2], xf[s4][3]);
          p2.h = __builtin_amdgcn_cvt_pkrtz(xf[s4][4], xf[s4][5]);
          p3.h = __builtin_amdgcn_cvt_pkrtz(xf[s4][6], xf[s4][7]);
          v = make_uint4(p0.u, p1.u, p2.u, p3.u);
        }
        *(uint4*)&xlds[(Q + 1) & 1][((row * 2 + cblk) * 130 + 1 + wp) * 8] = v;
      }
      __syncthreads();  // x(Q+1) writes + w(Q+1) DMA visible
    }
  }

  // ---- epilogue: C/D layout col = lane&31 (pixel), row = (reg&3)+8*(reg>>2)+4*half (o) ----
  int h = h0 + rw;
#pragma unroll
  for (int mt = 0; mt < 2; ++mt) {
#pragma unroll
    for (int i = 0; i < 2; ++i) {
      int p = np * 64 + i * 32 + l31;
      size_t ob = (size_t)nb * 64 * 16384 + (size_t)h * 128 + p;
#pragma unroll
      for (int reg = 0; reg < 16; ++reg) {
        int o = mt * 32 + (reg & 3) + 8 * (reg >> 2) + 4 * half;
        out[ob + (size_t)o * 16384] = acc[mt][i][reg] + bias[o];
      }
    }
  }
}

extern "C" void kernel_launch(void* const* d_in, const int* in_sizes, int n_in,
                              void* d_out, int out_size, void* d_ws, size_t ws_size,
                              hipStream_t stream) {
  const float* x = (const float*)d_in[0];
  const float* w = (const float*)d_in[1];
  const float* b = (const float*)d_in[2];
  float* out = (float*)d_out;
  u16* wbuf = (u16*)d_ws;  // 36864 fp16 = 73728 B of scratch

  prep_w<<<dim3(144), dim3(256), 0, stream>>>(w, wbuf);
  conv_mfma<<<dim3(2048), dim3(256), 0, stream>>>(x, wbuf, b, out);
}